// Round 9
// baseline (452.978 us; speedup 1.0000x reference)
//
#include <hip/hip_runtime.h>
#include <math.h>

#define NEG_CONST (-9000000000000000.0f)
#define SCARE 11.313708498984761f  // sqrt(128)

#define DPP_XOR1  0xB1   // quad_perm [1,0,3,2]
#define DPP_XOR2  0x4E   // quad_perm [2,3,0,1]
#define DPP_XOR7  0x141  // row_half_mirror
#define DPP_XOR15 0x140  // row_mirror

template<int CTRL>
__device__ __forceinline__ float dpp_add(float x) {
    int yi = __builtin_amdgcn_update_dpp(0, __float_as_int(x), CTRL, 0xF, 0xF, true);
    return x + __int_as_float(yi);
}
template<int CTRL>
__device__ __forceinline__ float dpp_max(float x) {
    int yi = __builtin_amdgcn_update_dpp(0, __float_as_int(x), CTRL, 0xF, 0xF, true);
    return fmaxf(x, __int_as_float(yi));
}

__device__ __forceinline__ void wave_vm_fence() {
    __builtin_amdgcn_wave_barrier();
    asm volatile("s_waitcnt vmcnt(0) lgkmcnt(0)" ::: "memory");
    __builtin_amdgcn_wave_barrier();
}

// ---- kernel 1: y=0: QKt = Q @ K^T ; y=1: VT = V^T  (grid (16,2)) ----
__global__ __launch_bounds__(256) void small_qkt_vt(const float* __restrict__ Q,
                                                    const float* __restrict__ K,
                                                    const float* __restrict__ V,
                                                    float* __restrict__ QKt,
                                                    float* __restrict__ VT) {
    int r  = blockIdx.x * 8 + (threadIdx.x >> 5);
    int c0 = (threadIdx.x & 31) * 4;
    if (blockIdx.y == 0) {
        float a0 = 0.f, a1 = 0.f, a2 = 0.f, a3 = 0.f;
        for (int k = 0; k < 128; k += 4) {
            float4 q  = *reinterpret_cast<const float4*>(&Q[r * 128 + k]);
            float4 k0 = *reinterpret_cast<const float4*>(&K[(c0 + 0) * 128 + k]);
            float4 k1 = *reinterpret_cast<const float4*>(&K[(c0 + 1) * 128 + k]);
            float4 k2 = *reinterpret_cast<const float4*>(&K[(c0 + 2) * 128 + k]);
            float4 k3 = *reinterpret_cast<const float4*>(&K[(c0 + 3) * 128 + k]);
            a0 += q.x*k0.x + q.y*k0.y + q.z*k0.z + q.w*k0.w;
            a1 += q.x*k1.x + q.y*k1.y + q.z*k1.z + q.w*k1.w;
            a2 += q.x*k2.x + q.y*k2.y + q.z*k2.z + q.w*k2.w;
            a3 += q.x*k3.x + q.y*k3.y + q.z*k3.z + q.w*k3.w;
        }
        float4 o = {a0, a1, a2, a3};
        *reinterpret_cast<float4*>(&QKt[r * 128 + c0]) = o;
    } else {
        float4 o;
        o.x = V[(c0 + 0) * 128 + r];
        o.y = V[(c0 + 1) * 128 + r];
        o.z = V[(c0 + 2) * 128 + r];
        o.w = V[(c0 + 3) * 128 + r];
        *reinterpret_cast<float4*>(&VT[r * 128 + c0]) = o;
    }
}

// ---- kernel 2: fused projections. Phase 1: xQK = x@QKt (pack x + xQK into G).
//      Phase 2: u = xQK @ V^T (re-stage acc through LDS, weights = VT). ----
__global__ __launch_bounds__(256) void proj_fused(
    const float* __restrict__ x,
    const float* __restrict__ QKt, const float* __restrict__ VT,
    float* __restrict__ G, float* __restrict__ u, int n)
{
    __shared__ __align__(16) float as_[32][132];  // [k][row] (transposed)
    __shared__ __align__(16) float wsd[32][132];  // [k][col]

    int row0 = blockIdx.x * 128;
    int tid = threadIdx.x;
    int tr = tid >> 4, tc = tid & 15;

    float acc[8][8] = {};
    for (int kk = 0; kk < 128; kk += 32) {
        #pragma unroll
        for (int it = 0; it < 4; ++it) {
            int id = tid + it * 256;
            int r = id >> 3;
            int f = id & 7;
            int grow = row0 + r;
            float4 v = (grow < n)
                ? *reinterpret_cast<const float4*>(&x[(size_t)grow * 128 + kk + f * 4])
                : make_float4(0.f, 0.f, 0.f, 0.f);
            as_[f * 4 + 0][r] = v.x; as_[f * 4 + 1][r] = v.y;
            as_[f * 4 + 2][r] = v.z; as_[f * 4 + 3][r] = v.w;
            if (grow < n)
                *reinterpret_cast<float4*>(&G[(size_t)grow * 256 + kk + f * 4]) = v;
        }
        #pragma unroll
        for (int it = 0; it < 4; ++it) {
            int id = tid + it * 256;
            int k = id >> 5;
            int c4 = id & 31;
            *reinterpret_cast<float4*>(&wsd[k][c4 * 4]) =
                *reinterpret_cast<const float4*>(&QKt[(size_t)(kk + k) * 128 + c4 * 4]);
        }
        __syncthreads();
        #pragma unroll 4
        for (int k = 0; k < 32; ++k) {
            float4 a0 = *reinterpret_cast<const float4*>(&as_[k][tr * 8]);
            float4 a1 = *reinterpret_cast<const float4*>(&as_[k][tr * 8 + 4]);
            float4 b0 = *reinterpret_cast<const float4*>(&wsd[k][tc * 8]);
            float4 b1 = *reinterpret_cast<const float4*>(&wsd[k][tc * 8 + 4]);
            float av[8] = {a0.x, a0.y, a0.z, a0.w, a1.x, a1.y, a1.z, a1.w};
            float bv[8] = {b0.x, b0.y, b0.z, b0.w, b1.x, b1.y, b1.z, b1.w};
            #pragma unroll
            for (int i2 = 0; i2 < 8; ++i2)
                #pragma unroll
                for (int j2 = 0; j2 < 8; ++j2)
                    acc[i2][j2] += av[i2] * bv[j2];
        }
        __syncthreads();
    }

    // write xQK half of G
    #pragma unroll
    for (int i2 = 0; i2 < 8; ++i2) {
        int grow = row0 + tr * 8 + i2;
        if (grow < n) {
            float4 o0 = {acc[i2][0], acc[i2][1], acc[i2][2], acc[i2][3]};
            float4 o1 = {acc[i2][4], acc[i2][5], acc[i2][6], acc[i2][7]};
            *reinterpret_cast<float4*>(&G[(size_t)grow * 256 + 128 + tc * 8])     = o0;
            *reinterpret_cast<float4*>(&G[(size_t)grow * 256 + 128 + tc * 8 + 4]) = o1;
        }
    }

    // phase 2: u = xQK @ V^T
    float acc2[8][8] = {};
    for (int kk = 0; kk < 128; kk += 32) {
        __syncthreads();
        int tcl = tc - (kk >> 3);
        if (tcl >= 0 && tcl < 4) {
            #pragma unroll
            for (int j2 = 0; j2 < 8; ++j2)
                #pragma unroll
                for (int i2 = 0; i2 < 8; ++i2)
                    as_[tcl * 8 + j2][tr * 8 + i2] = acc[i2][j2];
        }
        #pragma unroll
        for (int it = 0; it < 4; ++it) {
            int id = tid + it * 256;
            int k = id >> 5;
            int c4 = id & 31;
            *reinterpret_cast<float4*>(&wsd[k][c4 * 4]) =
                *reinterpret_cast<const float4*>(&VT[(size_t)(kk + k) * 128 + c4 * 4]);
        }
        __syncthreads();
        #pragma unroll 4
        for (int k = 0; k < 32; ++k) {
            float4 a0 = *reinterpret_cast<const float4*>(&as_[k][tr * 8]);
            float4 a1 = *reinterpret_cast<const float4*>(&as_[k][tr * 8 + 4]);
            float4 b0 = *reinterpret_cast<const float4*>(&wsd[k][tc * 8]);
            float4 b1 = *reinterpret_cast<const float4*>(&wsd[k][tc * 8 + 4]);
            float av[8] = {a0.x, a0.y, a0.z, a0.w, a1.x, a1.y, a1.z, a1.w};
            float bv[8] = {b0.x, b0.y, b0.z, b0.w, b1.x, b1.y, b1.z, b1.w};
            #pragma unroll
            for (int i2 = 0; i2 < 8; ++i2)
                #pragma unroll
                for (int j2 = 0; j2 < 8; ++j2)
                    acc2[i2][j2] += av[i2] * bv[j2];
        }
    }
    #pragma unroll
    for (int i2 = 0; i2 < 8; ++i2) {
        int grow = row0 + tr * 8 + i2;
        if (grow < n) {
            float4 o0 = {acc2[i2][0], acc2[i2][1], acc2[i2][2], acc2[i2][3]};
            float4 o1 = {acc2[i2][4], acc2[i2][5], acc2[i2][6], acc2[i2][7]};
            *reinterpret_cast<float4*>(&u[(size_t)grow * 128 + tc * 8])     = o0;
            *reinterpret_cast<float4*>(&u[(size_t)grow * 128 + tc * 8 + 4]) = o1;
        }
    }
}

// ---- kernel 3: per-node attention, 1 WAVE = 1 BLOCK = 1 node.
// t fused into stage-1 (same LDS B-reads feed both sc and tpart); no Ts, one fence.
__global__ __launch_bounds__(64, 4) void node_attn(
    const int* __restrict__ nlist,
    const float* __restrict__ G,
    float* uy,                      // in: u = xQK@V^T ; out: y (aliased)
    float* __restrict__ c0a,
    int n)
{
    __shared__ __align__(16) float Bs[2048];   // 16 rows x 128 floats (line-permuted)

    const int l  = threadIdx.x;   // 0..63
    const int g  = l >> 2;        // row/group 0..15
    const int jj = l & 3;         // 32-float chunk
    const int i  = blockIdx.x;

    int nlv = 0;
    if (l < 16) nlv = nlist[(size_t)i * 16 + l];
    unsigned long long mb = __ballot(l < 16 ? (nlv != n - 1) : 0);

    // async gather x-half of G[nl] -> LDS (8 instrs, 2 rows each)
    {
        int sub   = l & 31;                          // LDS line within row
        int sigma = ((sub & 3) << 3) | (sub >> 2);   // global line it must hold
        int half  = l >> 5;
        #pragma unroll
        for (int p = 0; p < 8; ++p) {
            int nr = __shfl(nlv, 2 * p + half, 64);
            const float* src = &G[(size_t)nr * 256 + sigma * 4];
            __builtin_amdgcn_global_load_lds(
                (const __attribute__((address_space(1))) unsigned int*)src,
                (__attribute__((address_space(3))) unsigned int*)&Bs[p * 256],
                16, 0, 0);
        }
    }

    // u chunk jj -> registers (overlaps the gather)
    float4 uu[8];
    {
        const float* ub = &uy[(size_t)i * 128 + jj * 32];
        #pragma unroll
        for (int k4 = 0; k4 < 8; ++k4)
            uu[k4] = *reinterpret_cast<const float4*>(&ub[k4 * 4]);
    }

    // s200 = xQK[i] . x[i] while the gather is in flight
    float2 qa = *reinterpret_cast<const float2*>(&G[(size_t)i * 256 + 128 + l * 2]);
    float2 xa = *reinterpret_cast<const float2*>(&G[(size_t)i * 256 + l * 2]);
    float s200 = qa.x * xa.x + qa.y * xa.y;
    s200 = dpp_add<DPP_XOR1>(s200);
    s200 = dpp_add<DPP_XOR2>(s200);
    s200 = dpp_add<DPP_XOR7>(s200);
    s200 = dpp_add<DPP_XOR15>(s200);
    s200 += __shfl_xor(s200, 16, 64);
    s200 += __shfl_xor(s200, 32, 64);

    // A = xQK[nl_g] chunk jj, overlaps the gather
    int nl_g = __shfl(nlv, g, 64);
    float4 A[8];
    {
        const float* ab = &G[(size_t)nl_g * 256 + 128 + jj * 32];
        #pragma unroll
        for (int k4 = 0; k4 < 8; ++k4)
            A[k4] = *reinterpret_cast<const float4*>(&ab[k4 * 4]);
    }

    wave_vm_fence();

    // stage-1: sc[c] = xQK[nl_g].x[nl_c]  AND  tv[c] = u[i].x[nl_c] (same B reads)
    float a[16];    // unnormalized softmax numerators p[c]
    float tv[16];
    float inv_s;    // 1/sum(p)
    {
        #pragma unroll
        for (int c = 0; c < 16; ++c) {
            const float* bb = &Bs[c * 128 + jj * 4];
            float accs = 0.f, acct = 0.f;
            #pragma unroll
            for (int k4 = 0; k4 < 8; ++k4) {
                float4 b = *reinterpret_cast<const float4*>(&bb[k4 * 16]);
                accs += A[k4].x * b.x + A[k4].y * b.y + A[k4].z * b.z + A[k4].w * b.w;
                acct += uu[k4].x * b.x + uu[k4].y * b.y + uu[k4].z * b.z + uu[k4].w * b.w;
            }
            accs = dpp_add<DPP_XOR1>(accs);
            accs = dpp_add<DPP_XOR2>(accs);
            acct = dpp_add<DPP_XOR1>(acct);
            acct = dpp_add<DPP_XOR2>(acct);
            a[c]  = accs;
            tv[c] = acct;
        }
        bool rlive = (mb >> g) & 1ULL;
        float m = -3.0e38f;
        #pragma unroll
        for (int c = 0; c < 16; ++c) {
            float s = a[c];
            float slr = s > 0.f ? s : 0.01f * s;
            bool live = rlive && ((mb >> c) & 1ULL);
            float sm = (live ? slr : NEG_CONST) * SCARE;
            a[c] = sm;
            m = fmaxf(m, sm);
        }
        float ssum = 0.f;
        #pragma unroll
        for (int c = 0; c < 16; ++c) { float p = __expf(a[c] - m); a[c] = p; ssum += p; }
        inv_s = 1.f / ssum;
    }

    // stage-2 logit for this group (j = g+1): scare -> leaky -> mask
    float lg = 0.f;
    #pragma unroll
    for (int k = 0; k < 16; ++k) lg += a[k] * tv[k];
    lg *= inv_s;
    {
        float v = lg * SCARE;
        v = v > 0.f ? v : 0.01f * v;
        lg = ((mb >> g) & 1ULL) ? v : NEG_CONST;
    }
    float v0 = s200 * SCARE;
    v0 = v0 > 0.f ? v0 : 0.01f * v0;

    float m17 = lg;
    m17 = dpp_max<DPP_XOR7>(m17);
    m17 = dpp_max<DPP_XOR15>(m17);
    m17 = fmaxf(m17, __shfl_xor(m17, 16, 64));
    m17 = fmaxf(m17, __shfl_xor(m17, 32, 64));
    m17 = fmaxf(m17, v0);
    float pg = __expf(lg - m17);
    float sg = pg;
    sg = dpp_add<DPP_XOR7>(sg);
    sg = dpp_add<DPP_XOR15>(sg);
    sg += __shfl_xor(sg, 16, 64);
    sg += __shfl_xor(sg, 32, 64);
    float p0 = __expf(v0 - m17);
    float inv2 = 1.f / (sg + p0);
    float a20 = p0 * inv2;
    float coeff = pg * inv2 * inv_s;   // a2[g+1]/ssum_g (replicated within quad)

    // w[k] = sum_g a2[g+1] * asm_g[k]   (exact 16-group sum via mirrors + shfl)
    float w[16];
    #pragma unroll
    for (int k = 0; k < 16; ++k) {
        float wv = coeff * a[k];
        wv = dpp_add<DPP_XOR7>(wv);
        wv = dpp_add<DPP_XOR15>(wv);
        wv += __shfl_xor(wv, 16, 64);
        wv += __shfl_xor(wv, 32, 64);
        w[k] = wv;
    }

    // y = sum_k w[k] * x[nl_k]; lane owns h = 2l,2l+1 (conflict-free float2 tiling)
    {
        int sg2 = l >> 1;                            // global 16B-line of element 2l
        int tau = ((sg2 & 7) << 2) | (sg2 >> 3);     // LDS line holding it
        int off2 = (2 * l) & 3;
        float y0 = 0.f, y1 = 0.f;
        #pragma unroll
        for (int k = 0; k < 16; ++k) {
            float2 bp = *reinterpret_cast<const float2*>(&Bs[k * 128 + tau * 4 + off2]);
            y0 += w[k] * bp.x;
            y1 += w[k] * bp.y;
        }
        float2 yw = {y0, y1};
        *reinterpret_cast<float2*>(&uy[(size_t)i * 128 + 2 * l]) = yw;
    }
    if (l == 0) c0a[i] = a20;
}

// ---- kernel 4: fused epilogue: out = normalize((c0*x + y@V) @ V) ----
__global__ __launch_bounds__(256) void ep_fused(
    const float* __restrict__ y, const float* __restrict__ G,
    const float* __restrict__ c0a, const float* __restrict__ Vw,
    float* __restrict__ outp, int n)
{
    __shared__ __align__(16) float as_[32][132];  // [k][row] (transposed)
    __shared__ __align__(16) float wsd[32][132];  // [k][col]

    int row0 = blockIdx.x * 128;
    int tid = threadIdx.x;
    int tr = tid >> 4, tc = tid & 15;

    float acc[8][8] = {};
    for (int kk = 0; kk < 128; kk += 32) {
        #pragma unroll
        for (int it = 0; it < 4; ++it) {
            int id = tid + it * 256;
            int r = id >> 3;
            int f = id & 7;
            int grow = row0 + r;
            float4 v = (grow < n)
                ? *reinterpret_cast<const float4*>(&y[(size_t)grow * 128 + kk + f * 4])
                : make_float4(0.f, 0.f, 0.f, 0.f);
            as_[f * 4 + 0][r] = v.x; as_[f * 4 + 1][r] = v.y;
            as_[f * 4 + 2][r] = v.z; as_[f * 4 + 3][r] = v.w;
        }
        #pragma unroll
        for (int it = 0; it < 4; ++it) {
            int id = tid + it * 256;
            int k = id >> 5;
            int c4 = id & 31;
            *reinterpret_cast<float4*>(&wsd[k][c4 * 4]) =
                *reinterpret_cast<const float4*>(&Vw[(size_t)(kk + k) * 128 + c4 * 4]);
        }
        __syncthreads();
        #pragma unroll 4
        for (int k = 0; k < 32; ++k) {
            float4 a0 = *reinterpret_cast<const float4*>(&as_[k][tr * 8]);
            float4 a1 = *reinterpret_cast<const float4*>(&as_[k][tr * 8 + 4]);
            float4 b0 = *reinterpret_cast<const float4*>(&wsd[k][tc * 8]);
            float4 b1 = *reinterpret_cast<const float4*>(&wsd[k][tc * 8 + 4]);
            float av[8] = {a0.x, a0.y, a0.z, a0.w, a1.x, a1.y, a1.z, a1.w};
            float bv[8] = {b0.x, b0.y, b0.z, b0.w, b1.x, b1.y, b1.z, b1.w};
            #pragma unroll
            for (int i2 = 0; i2 < 8; ++i2)
                #pragma unroll
                for (int j2 = 0; j2 < 8; ++j2)
                    acc[i2][j2] += av[i2] * bv[j2];
        }
        __syncthreads();
    }

    // t = acc + c0 * x   (x-half of G, stride 256)
    #pragma unroll
    for (int i2 = 0; i2 < 8; ++i2) {
        int grow = row0 + tr * 8 + i2;
        if (grow < n) {
            float c0v = c0a[grow];
            float4 g0 = *reinterpret_cast<const float4*>(&G[(size_t)grow * 256 + tc * 8]);
            float4 g1 = *reinterpret_cast<const float4*>(&G[(size_t)grow * 256 + tc * 8 + 4]);
            acc[i2][0] += c0v * g0.x; acc[i2][1] += c0v * g0.y;
            acc[i2][2] += c0v * g0.z; acc[i2][3] += c0v * g0.w;
            acc[i2][4] += c0v * g1.x; acc[i2][5] += c0v * g1.y;
            acc[i2][6] += c0v * g1.z; acc[i2][7] += c0v * g1.w;
        }
    }

    // phase 2: out = normalize(t @ V)
    float acc2[8][8] = {};
    for (int kk = 0; kk < 128; kk += 32) {
        __syncthreads();
        int tcl = tc - (kk >> 3);
        if (tcl >= 0 && tcl < 4) {
            #pragma unroll
            for (int j2 = 0; j2 < 8; ++j2)
                #pragma unroll
                for (int i2 = 0; i2 < 8; ++i2)
                    as_[tcl * 8 + j2][tr * 8 + i2] = acc[i2][j2];
        }
        #pragma unroll
        for (int it = 0; it < 4; ++it) {
            int id = tid + it * 256;
            int k = id >> 5;
            int c4 = id & 31;
            *reinterpret_cast<float4*>(&wsd[k][c4 * 4]) =
                *reinterpret_cast<const float4*>(&Vw[(size_t)(kk + k) * 128 + c4 * 4]);
        }
        __syncthreads();
        #pragma unroll 4
        for (int k = 0; k < 32; ++k) {
            float4 a0 = *reinterpret_cast<const float4*>(&as_[k][tr * 8]);
            float4 a1 = *reinterpret_cast<const float4*>(&as_[k][tr * 8 + 4]);
            float4 b0 = *reinterpret_cast<const float4*>(&wsd[k][tc * 8]);
            float4 b1 = *reinterpret_cast<const float4*>(&wsd[k][tc * 8 + 4]);
            float av[8] = {a0.x, a0.y, a0.z, a0.w, a1.x, a1.y, a1.z, a1.w};
            float bv[8] = {b0.x, b0.y, b0.z, b0.w, b1.x, b1.y, b1.z, b1.w};
            #pragma unroll
            for (int i2 = 0; i2 < 8; ++i2)
                #pragma unroll
                for (int j2 = 0; j2 < 8; ++j2)
                    acc2[i2][j2] += av[i2] * bv[j2];
        }
    }

    #pragma unroll
    for (int i2 = 0; i2 < 8; ++i2) {
        int grow = row0 + tr * 8 + i2;
        float ss = 0.f;
        #pragma unroll
        for (int j2 = 0; j2 < 8; ++j2) ss += acc2[i2][j2] * acc2[i2][j2];
        ss = dpp_add<DPP_XOR1>(ss);
        ss = dpp_add<DPP_XOR2>(ss);
        ss = dpp_add<DPP_XOR7>(ss);
        ss = dpp_add<DPP_XOR15>(ss);
        float d = fmaxf(sqrtf(ss), 1e-12f);
        float rd = 1.f / d;
        if (grow < n) {
            float4 o0 = {acc2[i2][0] * rd, acc2[i2][1] * rd, acc2[i2][2] * rd, acc2[i2][3] * rd};
            float4 o1 = {acc2[i2][4] * rd, acc2[i2][5] * rd, acc2[i2][6] * rd, acc2[i2][7] * rd};
            *reinterpret_cast<float4*>(&outp[(size_t)grow * 128 + tc * 8])     = o0;
            *reinterpret_cast<float4*>(&outp[(size_t)grow * 128 + tc * 8 + 4]) = o1;
        }
    }
}

extern "C" void kernel_launch(void* const* d_in, const int* in_sizes, int n_in,
                              void* d_out, int out_size, void* d_ws, size_t ws_size,
                              hipStream_t stream) {
    const float* x     = (const float*)d_in[0];
    const int*   nlist = (const int*)d_in[1];
    const float* Q     = (const float*)d_in[2];
    const float* K     = (const float*)d_in[3];
    const float* V     = (const float*)d_in[4];
    float* out = (float*)d_out;
    int n = in_sizes[0] / 128;   // 50000

    float* ws   = (float*)d_ws;
    float* QKt  = ws;                    // 16384
    float* VT   = ws + 16384;            // 16384
    float* c0a  = ws + 32768;            // n
    float* G    = c0a + n;               // n*256
    float* uarr = G + (size_t)n * 256;   // n*128  (y aliases this after node_attn)

    small_qkt_vt<<<dim3(16, 2), 256, 0, stream>>>(Q, K, V, QKt, VT);
    proj_fused<<<(n + 127) / 128, 256, 0, stream>>>(x, QKt, VT, G, uarr, n);
    node_attn<<<n, 64, 0, stream>>>(nlist, G, uarr, c0a, n);
    ep_fused<<<(n + 127) / 128, 256, 0, stream>>>(uarr, G, c0a, V, out, n);
}

// Round 10
// 286.880 us; speedup vs baseline: 1.5790x; 1.5790x over previous
//
#include <hip/hip_runtime.h>
#include <math.h>

#define NEG_CONST (-9000000000000000.0f)
#define SCARE 11.313708498984761f  // sqrt(128)

#define DPP_XOR1  0xB1   // quad_perm [1,0,3,2]
#define DPP_XOR2  0x4E   // quad_perm [2,3,0,1]
#define DPP_XOR7  0x141  // row_half_mirror
#define DPP_XOR15 0x140  // row_mirror

template<int CTRL>
__device__ __forceinline__ float dpp_add(float x) {
    int yi = __builtin_amdgcn_update_dpp(0, __float_as_int(x), CTRL, 0xF, 0xF, true);
    return x + __int_as_float(yi);
}
template<int CTRL>
__device__ __forceinline__ float dpp_max(float x) {
    int yi = __builtin_amdgcn_update_dpp(0, __float_as_int(x), CTRL, 0xF, 0xF, true);
    return fmaxf(x, __int_as_float(yi));
}

__device__ __forceinline__ void wave_lds_fence() {
    __builtin_amdgcn_wave_barrier();
    asm volatile("s_waitcnt lgkmcnt(0)" ::: "memory");
    __builtin_amdgcn_wave_barrier();
}
__device__ __forceinline__ void wave_vm_fence() {
    __builtin_amdgcn_wave_barrier();
    asm volatile("s_waitcnt vmcnt(0) lgkmcnt(0)" ::: "memory");
    __builtin_amdgcn_wave_barrier();
}

// ---- kernel 1: y=0: QKt = Q @ K^T ; y=1: VT = V^T  (grid (16,2)) ----
__global__ __launch_bounds__(256) void small_qkt_vt(const float* __restrict__ Q,
                                                    const float* __restrict__ K,
                                                    const float* __restrict__ V,
                                                    float* __restrict__ QKt,
                                                    float* __restrict__ VT) {
    int r  = blockIdx.x * 8 + (threadIdx.x >> 5);
    int c0 = (threadIdx.x & 31) * 4;
    if (blockIdx.y == 0) {
        float a0 = 0.f, a1 = 0.f, a2 = 0.f, a3 = 0.f;
        for (int k = 0; k < 128; k += 4) {
            float4 q  = *reinterpret_cast<const float4*>(&Q[r * 128 + k]);
            float4 k0 = *reinterpret_cast<const float4*>(&K[(c0 + 0) * 128 + k]);
            float4 k1 = *reinterpret_cast<const float4*>(&K[(c0 + 1) * 128 + k]);
            float4 k2 = *reinterpret_cast<const float4*>(&K[(c0 + 2) * 128 + k]);
            float4 k3 = *reinterpret_cast<const float4*>(&K[(c0 + 3) * 128 + k]);
            a0 += q.x*k0.x + q.y*k0.y + q.z*k0.z + q.w*k0.w;
            a1 += q.x*k1.x + q.y*k1.y + q.z*k1.z + q.w*k1.w;
            a2 += q.x*k2.x + q.y*k2.y + q.z*k2.z + q.w*k2.w;
            a3 += q.x*k3.x + q.y*k3.y + q.z*k3.z + q.w*k3.w;
        }
        float4 o = {a0, a1, a2, a3};
        *reinterpret_cast<float4*>(&QKt[r * 128 + c0]) = o;
    } else {
        float4 o;
        o.x = V[(c0 + 0) * 128 + r];
        o.y = V[(c0 + 1) * 128 + r];
        o.z = V[(c0 + 2) * 128 + r];
        o.w = V[(c0 + 3) * 128 + r];
        *reinterpret_cast<float4*>(&VT[r * 128 + c0]) = o;
    }
}

// ---- kernel 2: fused projections. Phase 1: xQK = x@QKt (pack x + xQK into G).
//      Phase 2: u = xQK @ V^T (re-stage acc through LDS, weights = VT). ----
__global__ __launch_bounds__(256) void proj_fused(
    const float* __restrict__ x,
    const float* __restrict__ QKt, const float* __restrict__ VT,
    float* __restrict__ G, float* __restrict__ u, int n)
{
    __shared__ __align__(16) float as_[32][132];  // [k][row] (transposed)
    __shared__ __align__(16) float wsd[32][132];  // [k][col]

    int row0 = blockIdx.x * 128;
    int tid = threadIdx.x;
    int tr = tid >> 4, tc = tid & 15;

    float acc[8][8] = {};
    for (int kk = 0; kk < 128; kk += 32) {
        #pragma unroll
        for (int it = 0; it < 4; ++it) {
            int id = tid + it * 256;
            int r = id >> 3;
            int f = id & 7;
            int grow = row0 + r;
            float4 v = (grow < n)
                ? *reinterpret_cast<const float4*>(&x[(size_t)grow * 128 + kk + f * 4])
                : make_float4(0.f, 0.f, 0.f, 0.f);
            as_[f * 4 + 0][r] = v.x; as_[f * 4 + 1][r] = v.y;
            as_[f * 4 + 2][r] = v.z; as_[f * 4 + 3][r] = v.w;
            if (grow < n)
                *reinterpret_cast<float4*>(&G[(size_t)grow * 256 + kk + f * 4]) = v;
        }
        #pragma unroll
        for (int it = 0; it < 4; ++it) {
            int id = tid + it * 256;
            int k = id >> 5;
            int c4 = id & 31;
            *reinterpret_cast<float4*>(&wsd[k][c4 * 4]) =
                *reinterpret_cast<const float4*>(&QKt[(size_t)(kk + k) * 128 + c4 * 4]);
        }
        __syncthreads();
        #pragma unroll 4
        for (int k = 0; k < 32; ++k) {
            float4 a0 = *reinterpret_cast<const float4*>(&as_[k][tr * 8]);
            float4 a1 = *reinterpret_cast<const float4*>(&as_[k][tr * 8 + 4]);
            float4 b0 = *reinterpret_cast<const float4*>(&wsd[k][tc * 8]);
            float4 b1 = *reinterpret_cast<const float4*>(&wsd[k][tc * 8 + 4]);
            float av[8] = {a0.x, a0.y, a0.z, a0.w, a1.x, a1.y, a1.z, a1.w};
            float bv[8] = {b0.x, b0.y, b0.z, b0.w, b1.x, b1.y, b1.z, b1.w};
            #pragma unroll
            for (int i2 = 0; i2 < 8; ++i2)
                #pragma unroll
                for (int j2 = 0; j2 < 8; ++j2)
                    acc[i2][j2] += av[i2] * bv[j2];
        }
        __syncthreads();
    }

    // write xQK half of G
    #pragma unroll
    for (int i2 = 0; i2 < 8; ++i2) {
        int grow = row0 + tr * 8 + i2;
        if (grow < n) {
            float4 o0 = {acc[i2][0], acc[i2][1], acc[i2][2], acc[i2][3]};
            float4 o1 = {acc[i2][4], acc[i2][5], acc[i2][6], acc[i2][7]};
            *reinterpret_cast<float4*>(&G[(size_t)grow * 256 + 128 + tc * 8])     = o0;
            *reinterpret_cast<float4*>(&G[(size_t)grow * 256 + 128 + tc * 8 + 4]) = o1;
        }
    }

    // phase 2: u = xQK @ V^T
    float acc2[8][8] = {};
    for (int kk = 0; kk < 128; kk += 32) {
        __syncthreads();
        int tcl = tc - (kk >> 3);
        if (tcl >= 0 && tcl < 4) {
            #pragma unroll
            for (int j2 = 0; j2 < 8; ++j2)
                #pragma unroll
                for (int i2 = 0; i2 < 8; ++i2)
                    as_[tcl * 8 + j2][tr * 8 + i2] = acc[i2][j2];
        }
        #pragma unroll
        for (int it = 0; it < 4; ++it) {
            int id = tid + it * 256;
            int k = id >> 5;
            int c4 = id & 31;
            *reinterpret_cast<float4*>(&wsd[k][c4 * 4]) =
                *reinterpret_cast<const float4*>(&VT[(size_t)(kk + k) * 128 + c4 * 4]);
        }
        __syncthreads();
        #pragma unroll 4
        for (int k = 0; k < 32; ++k) {
            float4 a0 = *reinterpret_cast<const float4*>(&as_[k][tr * 8]);
            float4 a1 = *reinterpret_cast<const float4*>(&as_[k][tr * 8 + 4]);
            float4 b0 = *reinterpret_cast<const float4*>(&wsd[k][tc * 8]);
            float4 b1 = *reinterpret_cast<const float4*>(&wsd[k][tc * 8 + 4]);
            float av[8] = {a0.x, a0.y, a0.z, a0.w, a1.x, a1.y, a1.z, a1.w};
            float bv[8] = {b0.x, b0.y, b0.z, b0.w, b1.x, b1.y, b1.z, b1.w};
            #pragma unroll
            for (int i2 = 0; i2 < 8; ++i2)
                #pragma unroll
                for (int j2 = 0; j2 < 8; ++j2)
                    acc2[i2][j2] += av[i2] * bv[j2];
        }
    }
    #pragma unroll
    for (int i2 = 0; i2 < 8; ++i2) {
        int grow = row0 + tr * 8 + i2;
        if (grow < n) {
            float4 o0 = {acc2[i2][0], acc2[i2][1], acc2[i2][2], acc2[i2][3]};
            float4 o1 = {acc2[i2][4], acc2[i2][5], acc2[i2][6], acc2[i2][7]};
            *reinterpret_cast<float4*>(&u[(size_t)grow * 128 + tc * 8])     = o0;
            *reinterpret_cast<float4*>(&u[(size_t)grow * 128 + tc * 8 + 4]) = o1;
        }
    }
}

// ---- kernel 3: per-node attention, 1 WAVE = 1 BLOCK = 1 node (R7 structure,
//      conflict-free line-parallel y-loop) ----
__global__ __launch_bounds__(64, 5) void node_attn(
    const int* __restrict__ nlist,
    const float* __restrict__ G,
    float* uy,                      // in: u = xQK@V^T ; out: y (aliased)
    float* __restrict__ c0a,
    int n)
{
    __shared__ __align__(16) float Bs[2048];   // 16 rows x 128 floats (line-permuted)
    __shared__ __align__(16) float Ts[16];

    const int l  = threadIdx.x;   // 0..63
    const int g  = l >> 2;        // row/group 0..15
    const int jj = l & 3;         // 32-float chunk
    const int i  = blockIdx.x;

    int nlv = 0;
    if (l < 16) nlv = nlist[(size_t)i * 16 + l];
    unsigned long long mb = __ballot(l < 16 ? (nlv != n - 1) : 0);

    // async gather x-half of G[nl] -> LDS (8 instrs, 2 rows each)
    {
        int sub   = l & 31;                          // LDS line within row
        int sigma = ((sub & 3) << 3) | (sub >> 2);   // global line it must hold
        int half  = l >> 5;
        #pragma unroll
        for (int p = 0; p < 8; ++p) {
            int nr = __shfl(nlv, 2 * p + half, 64);
            const float* src = &G[(size_t)nr * 256 + sigma * 4];
            __builtin_amdgcn_global_load_lds(
                (const __attribute__((address_space(1))) unsigned int*)src,
                (__attribute__((address_space(3))) unsigned int*)&Bs[p * 256],
                16, 0, 0);
        }
    }

    // s200 = xQK[i] . x[i] while the gather is in flight
    float2 qa = *reinterpret_cast<const float2*>(&G[(size_t)i * 256 + 128 + l * 2]);
    float2 xa = *reinterpret_cast<const float2*>(&G[(size_t)i * 256 + l * 2]);
    float s200 = qa.x * xa.x + qa.y * xa.y;
    s200 = dpp_add<DPP_XOR1>(s200);
    s200 = dpp_add<DPP_XOR2>(s200);
    s200 = dpp_add<DPP_XOR7>(s200);
    s200 = dpp_add<DPP_XOR15>(s200);
    s200 += __shfl_xor(s200, 16, 64);
    s200 += __shfl_xor(s200, 32, 64);

    // A = xQK[nl_g] chunk jj (k-ascending), overlaps the gather
    int nl_g = __shfl(nlv, g, 64);
    float4 A[8];
    {
        const float* ab = &G[(size_t)nl_g * 256 + 128 + jj * 32];
        #pragma unroll
        for (int k4 = 0; k4 < 8; ++k4)
            A[k4] = *reinterpret_cast<const float4*>(&ab[k4 * 4]);
    }

    wave_vm_fence();

    // stage-1: sc[c] = xQK[nl_g] . x[nl_c]; leaky -> mask -> *scare -> row softmax
    float a[16];
    {
        float sc[16];
        #pragma unroll
        for (int c = 0; c < 16; ++c) {
            const float* bb = &Bs[c * 128 + jj * 4];
            float acc = 0.f;
            #pragma unroll
            for (int k4 = 0; k4 < 8; ++k4) {
                float4 b = *reinterpret_cast<const float4*>(&bb[k4 * 16]);
                acc += A[k4].x * b.x + A[k4].y * b.y + A[k4].z * b.z + A[k4].w * b.w;
            }
            acc = dpp_add<DPP_XOR1>(acc);
            acc = dpp_add<DPP_XOR2>(acc);
            sc[c] = acc;
        }
        bool rlive = (mb >> g) & 1ULL;
        float m = -3.0e38f;
        #pragma unroll
        for (int c = 0; c < 16; ++c) {
            float s = sc[c];
            float slr = s > 0.f ? s : 0.01f * s;
            bool live = rlive && ((mb >> c) & 1ULL);
            float sm = (live ? slr : NEG_CONST) * SCARE;
            sc[c] = sm;
            m = fmaxf(m, sm);
        }
        float ssum = 0.f;
        #pragma unroll
        for (int c = 0; c < 16; ++c) { float p = __expf(sc[c] - m); a[c] = p; ssum += p; }
        float rs = 1.f / ssum;
        #pragma unroll
        for (int c = 0; c < 16; ++c) a[c] *= rs;
    }

    // t_g = u[i] . x[nl_g]  (k4 staggered by g; 8 lanes per 4-bank group = floor)
    {
        float acc = 0.f;
        #pragma unroll
        for (int k4 = 0; k4 < 8; ++k4) {
            int kx = (k4 + g) & 7;
            float4 b  = *reinterpret_cast<const float4*>(&Bs[g * 128 + kx * 16 + jj * 4]);
            float4 uu = *reinterpret_cast<const float4*>(&uy[(size_t)i * 128 + jj * 32 + kx * 4]);
            acc += uu.x * b.x + uu.y * b.y + uu.z * b.z + uu.w * b.w;
        }
        acc = dpp_add<DPP_XOR1>(acc);
        acc = dpp_add<DPP_XOR2>(acc);
        if (jj == 0) Ts[g] = acc;
    }
    wave_lds_fence();
    float tarr[16];
    {
        #pragma unroll
        for (int q4 = 0; q4 < 4; ++q4) {
            float4 t4 = *reinterpret_cast<const float4*>(&Ts[q4 * 4]);
            tarr[q4 * 4 + 0] = t4.x; tarr[q4 * 4 + 1] = t4.y;
            tarr[q4 * 4 + 2] = t4.z; tarr[q4 * 4 + 3] = t4.w;
        }
    }

    // stage-2 logit for this group (j = g+1): scare -> leaky -> mask
    float lg = 0.f;
    #pragma unroll
    for (int k = 0; k < 16; ++k) lg += a[k] * tarr[k];
    {
        float v = lg * SCARE;
        v = v > 0.f ? v : 0.01f * v;
        lg = ((mb >> g) & 1ULL) ? v : NEG_CONST;
    }
    float v0 = s200 * SCARE;
    v0 = v0 > 0.f ? v0 : 0.01f * v0;

    float m17 = lg;
    m17 = dpp_max<DPP_XOR7>(m17);
    m17 = dpp_max<DPP_XOR15>(m17);
    m17 = fmaxf(m17, __shfl_xor(m17, 16, 64));
    m17 = fmaxf(m17, __shfl_xor(m17, 32, 64));
    m17 = fmaxf(m17, v0);
    float pg = __expf(lg - m17);
    float sg = pg;
    sg = dpp_add<DPP_XOR7>(sg);
    sg = dpp_add<DPP_XOR15>(sg);
    sg += __shfl_xor(sg, 16, 64);
    sg += __shfl_xor(sg, 32, 64);
    float p0 = __expf(v0 - m17);
    float inv = 1.f / (sg + p0);
    float a2g = pg * inv;   // a2[g+1] (replicated within quad)
    float a20 = p0 * inv;

    // w[k] = sum_g a2[g+1] * a[g][k]
    float w[16];
    #pragma unroll
    for (int k = 0; k < 16; ++k) {
        float wv = a2g * a[k];
        wv = dpp_add<DPP_XOR7>(wv);
        wv = dpp_add<DPP_XOR15>(wv);
        wv += __shfl_xor(wv, 16, 64);
        wv += __shfl_xor(wv, 32, 64);
        w[k] = wv;
    }

    // y-loop, line-parallel: lane (h=l>>5, tau=l&31) accumulates the 16B line tau
    // over its half of the rows via b128 (8 lanes/4-bank group = exact floor),
    // combine halves with one shfl_xor(32), h==0 lanes write permuted float4.
    {
        int h   = l >> 5;
        int tau = l & 31;
        float y0 = 0.f, y1 = 0.f, y2 = 0.f, y3 = 0.f;
        #pragma unroll
        for (int k = 0; k < 8; ++k) {
            float wk = h ? w[k + 8] : w[k];
            const float* bp = &Bs[(h * 8 + k) * 128 + tau * 4];
            float4 b = *reinterpret_cast<const float4*>(bp);
            y0 += wk * b.x; y1 += wk * b.y; y2 += wk * b.z; y3 += wk * b.w;
        }
        y0 += __shfl_xor(y0, 32, 64);
        y1 += __shfl_xor(y1, 32, 64);
        y2 += __shfl_xor(y2, 32, 64);
        y3 += __shfl_xor(y3, 32, 64);
        if (h == 0) {
            int sigma = ((tau & 3) << 3) | (tau >> 2);   // global line held by tau
            float4 yw = {y0, y1, y2, y3};
            *reinterpret_cast<float4*>(&uy[(size_t)i * 128 + sigma * 4]) = yw;
        }
    }
    if (l == 0) c0a[i] = a20;
}

// ---- kernel 4: fused epilogue: out = normalize((c0*x + y@V) @ V) ----
__global__ __launch_bounds__(256) void ep_fused(
    const float* __restrict__ y, const float* __restrict__ G,
    const float* __restrict__ c0a, const float* __restrict__ Vw,
    float* __restrict__ outp, int n)
{
    __shared__ __align__(16) float as_[32][132];  // [k][row] (transposed)
    __shared__ __align__(16) float wsd[32][132];  // [k][col]

    int row0 = blockIdx.x * 128;
    int tid = threadIdx.x;
    int tr = tid >> 4, tc = tid & 15;

    float acc[8][8] = {};
    for (int kk = 0; kk < 128; kk += 32) {
        #pragma unroll
        for (int it = 0; it < 4; ++it) {
            int id = tid + it * 256;
            int r = id >> 3;
            int f = id & 7;
            int grow = row0 + r;
            float4 v = (grow < n)
                ? *reinterpret_cast<const float4*>(&y[(size_t)grow * 128 + kk + f * 4])
                : make_float4(0.f, 0.f, 0.f, 0.f);
            as_[f * 4 + 0][r] = v.x; as_[f * 4 + 1][r] = v.y;
            as_[f * 4 + 2][r] = v.z; as_[f * 4 + 3][r] = v.w;
        }
        #pragma unroll
        for (int it = 0; it < 4; ++it) {
            int id = tid + it * 256;
            int k = id >> 5;
            int c4 = id & 31;
            *reinterpret_cast<float4*>(&wsd[k][c4 * 4]) =
                *reinterpret_cast<const float4*>(&Vw[(size_t)(kk + k) * 128 + c4 * 4]);
        }
        __syncthreads();
        #pragma unroll 4
        for (int k = 0; k < 32; ++k) {
            float4 a0 = *reinterpret_cast<const float4*>(&as_[k][tr * 8]);
            float4 a1 = *reinterpret_cast<const float4*>(&as_[k][tr * 8 + 4]);
            float4 b0 = *reinterpret_cast<const float4*>(&wsd[k][tc * 8]);
            float4 b1 = *reinterpret_cast<const float4*>(&wsd[k][tc * 8 + 4]);
            float av[8] = {a0.x, a0.y, a0.z, a0.w, a1.x, a1.y, a1.z, a1.w};
            float bv[8] = {b0.x, b0.y, b0.z, b0.w, b1.x, b1.y, b1.z, b1.w};
            #pragma unroll
            for (int i2 = 0; i2 < 8; ++i2)
                #pragma unroll
                for (int j2 = 0; j2 < 8; ++j2)
                    acc[i2][j2] += av[i2] * bv[j2];
        }
        __syncthreads();
    }

    // t = acc + c0 * x   (x-half of G, stride 256)
    #pragma unroll
    for (int i2 = 0; i2 < 8; ++i2) {
        int grow = row0 + tr * 8 + i2;
        if (grow < n) {
            float c0v = c0a[grow];
            float4 g0 = *reinterpret_cast<const float4*>(&G[(size_t)grow * 256 + tc * 8]);
            float4 g1 = *reinterpret_cast<const float4*>(&G[(size_t)grow * 256 + tc * 8 + 4]);
            acc[i2][0] += c0v * g0.x; acc[i2][1] += c0v * g0.y;
            acc[i2][2] += c0v * g0.z; acc[i2][3] += c0v * g0.w;
            acc[i2][4] += c0v * g1.x; acc[i2][5] += c0v * g1.y;
            acc[i2][6] += c0v * g1.z; acc[i2][7] += c0v * g1.w;
        }
    }

    // phase 2: out = normalize(t @ V)
    float acc2[8][8] = {};
    for (int kk = 0; kk < 128; kk += 32) {
        __syncthreads();
        int tcl = tc - (kk >> 3);
        if (tcl >= 0 && tcl < 4) {
            #pragma unroll
            for (int j2 = 0; j2 < 8; ++j2)
                #pragma unroll
                for (int i2 = 0; i2 < 8; ++i2)
                    as_[tcl * 8 + j2][tr * 8 + i2] = acc[i2][j2];
        }
        #pragma unroll
        for (int it = 0; it < 4; ++it) {
            int id = tid + it * 256;
            int k = id >> 5;
            int c4 = id & 31;
            *reinterpret_cast<float4*>(&wsd[k][c4 * 4]) =
                *reinterpret_cast<const float4*>(&Vw[(size_t)(kk + k) * 128 + c4 * 4]);
        }
        __syncthreads();
        #pragma unroll 4
        for (int k = 0; k < 32; ++k) {
            float4 a0 = *reinterpret_cast<const float4*>(&as_[k][tr * 8]);
            float4 a1 = *reinterpret_cast<const float4*>(&as_[k][tr * 8 + 4]);
            float4 b0 = *reinterpret_cast<const float4*>(&wsd[k][tc * 8]);
            float4 b1 = *reinterpret_cast<const float4*>(&wsd[k][tc * 8 + 4]);
            float av[8] = {a0.x, a0.y, a0.z, a0.w, a1.x, a1.y, a1.z, a1.w};
            float bv[8] = {b0.x, b0.y, b0.z, b0.w, b1.x, b1.y, b1.z, b1.w};
            #pragma unroll
            for (int i2 = 0; i2 < 8; ++i2)
                #pragma unroll
                for (int j2 = 0; j2 < 8; ++j2)
                    acc2[i2][j2] += av[i2] * bv[j2];
        }
    }

    #pragma unroll
    for (int i2 = 0; i2 < 8; ++i2) {
        int grow = row0 + tr * 8 + i2;
        float ss = 0.f;
        #pragma unroll
        for (int j2 = 0; j2 < 8; ++j2) ss += acc2[i2][j2] * acc2[i2][j2];
        ss = dpp_add<DPP_XOR1>(ss);
        ss = dpp_add<DPP_XOR2>(ss);
        ss = dpp_add<DPP_XOR7>(ss);
        ss = dpp_add<DPP_XOR15>(ss);
        float d = fmaxf(sqrtf(ss), 1e-12f);
        float rd = 1.f / d;
        if (grow < n) {
            float4 o0 = {acc2[i2][0] * rd, acc2[i2][1] * rd, acc2[i2][2] * rd, acc2[i2][3] * rd};
            float4 o1 = {acc2[i2][4] * rd, acc2[i2][5] * rd, acc2[i2][6] * rd, acc2[i2][7] * rd};
            *reinterpret_cast<float4*>(&outp[(size_t)grow * 128 + tc * 8])     = o0;
            *reinterpret_cast<float4*>(&outp[(size_t)grow * 128 + tc * 8 + 4]) = o1;
        }
    }
}

extern "C" void kernel_launch(void* const* d_in, const int* in_sizes, int n_in,
                              void* d_out, int out_size, void* d_ws, size_t ws_size,
                              hipStream_t stream) {
    const float* x     = (const float*)d_in[0];
    const int*   nlist = (const int*)d_in[1];
    const float* Q     = (const float*)d_in[2];
    const float* K     = (const float*)d_in[3];
    const float* V     = (const float*)d_in[4];
    float* out = (float*)d_out;
    int n = in_sizes[0] / 128;   // 50000

    float* ws   = (float*)d_ws;
    float* QKt  = ws;                    // 16384
    float* VT   = ws + 16384;            // 16384
    float* c0a  = ws + 32768;            // n
    float* G    = c0a + n;               // n*256
    float* uarr = G + (size_t)n * 256;   // n*128  (y aliases this after node_attn)

    small_qkt_vt<<<dim3(16, 2), 256, 0, stream>>>(Q, K, V, QKt, VT);
    proj_fused<<<(n + 127) / 128, 256, 0, stream>>>(x, QKt, VT, G, uarr, n);
    node_attn<<<n, 64, 0, stream>>>(nlist, G, uarr, c0a, n);
    ep_fused<<<(n + 127) / 128, 256, 0, stream>>>(uarr, G, c0a, V, out, n);
}

// Round 11
// 285.931 us; speedup vs baseline: 1.5842x; 1.0033x over previous
//
#include <hip/hip_runtime.h>
#include <math.h>

#define NEG_CONST (-9000000000000000.0f)
#define SCARE 11.313708498984761f  // sqrt(128)

#define DPP_XOR1  0xB1   // quad_perm [1,0,3,2]
#define DPP_XOR2  0x4E   // quad_perm [2,3,0,1]
#define DPP_XOR7  0x141  // row_half_mirror
#define DPP_XOR15 0x140  // row_mirror

template<int CTRL>
__device__ __forceinline__ float dpp_add(float x) {
    int yi = __builtin_amdgcn_update_dpp(0, __float_as_int(x), CTRL, 0xF, 0xF, true);
    return x + __int_as_float(yi);
}
template<int CTRL>
__device__ __forceinline__ float dpp_max(float x) {
    int yi = __builtin_amdgcn_update_dpp(0, __float_as_int(x), CTRL, 0xF, 0xF, true);
    return fmaxf(x, __int_as_float(yi));
}

__device__ __forceinline__ void wave_lds_fence() {
    __builtin_amdgcn_wave_barrier();
    asm volatile("s_waitcnt lgkmcnt(0)" ::: "memory");
    __builtin_amdgcn_wave_barrier();
}
__device__ __forceinline__ void wave_vm_fence() {
    __builtin_amdgcn_wave_barrier();
    asm volatile("s_waitcnt vmcnt(0) lgkmcnt(0)" ::: "memory");
    __builtin_amdgcn_wave_barrier();
}

// ---- kernel 1: y=0: QKt = Q @ K^T ; y=1: VT = V^T  (grid (16,2)) ----
__global__ __launch_bounds__(256) void small_qkt_vt(const float* __restrict__ Q,
                                                    const float* __restrict__ K,
                                                    const float* __restrict__ V,
                                                    float* __restrict__ QKt,
                                                    float* __restrict__ VT) {
    int r  = blockIdx.x * 8 + (threadIdx.x >> 5);
    int c0 = (threadIdx.x & 31) * 4;
    if (blockIdx.y == 0) {
        float a0 = 0.f, a1 = 0.f, a2 = 0.f, a3 = 0.f;
        for (int k = 0; k < 128; k += 4) {
            float4 q  = *reinterpret_cast<const float4*>(&Q[r * 128 + k]);
            float4 k0 = *reinterpret_cast<const float4*>(&K[(c0 + 0) * 128 + k]);
            float4 k1 = *reinterpret_cast<const float4*>(&K[(c0 + 1) * 128 + k]);
            float4 k2 = *reinterpret_cast<const float4*>(&K[(c0 + 2) * 128 + k]);
            float4 k3 = *reinterpret_cast<const float4*>(&K[(c0 + 3) * 128 + k]);
            a0 += q.x*k0.x + q.y*k0.y + q.z*k0.z + q.w*k0.w;
            a1 += q.x*k1.x + q.y*k1.y + q.z*k1.z + q.w*k1.w;
            a2 += q.x*k2.x + q.y*k2.y + q.z*k2.z + q.w*k2.w;
            a3 += q.x*k3.x + q.y*k3.y + q.z*k3.z + q.w*k3.w;
        }
        float4 o = {a0, a1, a2, a3};
        *reinterpret_cast<float4*>(&QKt[r * 128 + c0]) = o;
    } else {
        float4 o;
        o.x = V[(c0 + 0) * 128 + r];
        o.y = V[(c0 + 1) * 128 + r];
        o.z = V[(c0 + 2) * 128 + r];
        o.w = V[(c0 + 3) * 128 + r];
        *reinterpret_cast<float4*>(&VT[r * 128 + c0]) = o;
    }
}

// B-tile slot de-interleave: float4 column c4 stored at slot ((c4&1)<<4)|(c4>>1).
// Compute reads become contiguous-16-line b128 reads (slots tc and 16+tc) -> 0 conflicts.

// ---- kernel 2: fused projections. Phase 1: xQK = x@QKt (pack x + xQK into G).
//      Phase 2: u = xQK @ V^T (re-stage acc through LDS, weights = VT). ----
__global__ __launch_bounds__(256) void proj_fused(
    const float* __restrict__ x,
    const float* __restrict__ QKt, const float* __restrict__ VT,
    float* __restrict__ G, float* __restrict__ u, int n)
{
    __shared__ __align__(16) float as_[32][132];  // [k][row] (transposed)
    __shared__ __align__(16) float wsd[32][132];  // [k][slot] (de-interleaved)

    int row0 = blockIdx.x * 128;
    int tid = threadIdx.x;
    int tr = tid >> 4, tc = tid & 15;

    float acc[8][8] = {};
    for (int kk = 0; kk < 128; kk += 32) {
        #pragma unroll
        for (int it = 0; it < 4; ++it) {
            int id = tid + it * 256;
            int r = id >> 3;
            int f = id & 7;
            int grow = row0 + r;
            float4 v = (grow < n)
                ? *reinterpret_cast<const float4*>(&x[(size_t)grow * 128 + kk + f * 4])
                : make_float4(0.f, 0.f, 0.f, 0.f);
            as_[f * 4 + 0][r] = v.x; as_[f * 4 + 1][r] = v.y;
            as_[f * 4 + 2][r] = v.z; as_[f * 4 + 3][r] = v.w;
            if (grow < n)
                *reinterpret_cast<float4*>(&G[(size_t)grow * 256 + kk + f * 4]) = v;
        }
        #pragma unroll
        for (int it = 0; it < 4; ++it) {
            int id = tid + it * 256;
            int k = id >> 5;
            int c4 = id & 31;
            int s4 = ((c4 & 1) << 4) | (c4 >> 1);
            *reinterpret_cast<float4*>(&wsd[k][s4 * 4]) =
                *reinterpret_cast<const float4*>(&QKt[(size_t)(kk + k) * 128 + c4 * 4]);
        }
        __syncthreads();
        #pragma unroll 4
        for (int k = 0; k < 32; ++k) {
            float4 a0 = *reinterpret_cast<const float4*>(&as_[k][tr * 8]);
            float4 a1 = *reinterpret_cast<const float4*>(&as_[k][tr * 8 + 4]);
            float4 b0 = *reinterpret_cast<const float4*>(&wsd[k][tc * 4]);
            float4 b1 = *reinterpret_cast<const float4*>(&wsd[k][64 + tc * 4]);
            float av[8] = {a0.x, a0.y, a0.z, a0.w, a1.x, a1.y, a1.z, a1.w};
            float bv[8] = {b0.x, b0.y, b0.z, b0.w, b1.x, b1.y, b1.z, b1.w};
            #pragma unroll
            for (int i2 = 0; i2 < 8; ++i2)
                #pragma unroll
                for (int j2 = 0; j2 < 8; ++j2)
                    acc[i2][j2] += av[i2] * bv[j2];
        }
        __syncthreads();
    }

    // write xQK half of G
    #pragma unroll
    for (int i2 = 0; i2 < 8; ++i2) {
        int grow = row0 + tr * 8 + i2;
        if (grow < n) {
            float4 o0 = {acc[i2][0], acc[i2][1], acc[i2][2], acc[i2][3]};
            float4 o1 = {acc[i2][4], acc[i2][5], acc[i2][6], acc[i2][7]};
            *reinterpret_cast<float4*>(&G[(size_t)grow * 256 + 128 + tc * 8])     = o0;
            *reinterpret_cast<float4*>(&G[(size_t)grow * 256 + 128 + tc * 8 + 4]) = o1;
        }
    }

    // phase 2: u = xQK @ V^T
    float acc2[8][8] = {};
    for (int kk = 0; kk < 128; kk += 32) {
        __syncthreads();
        int tcl = tc - (kk >> 3);
        if (tcl >= 0 && tcl < 4) {
            #pragma unroll
            for (int j2 = 0; j2 < 8; ++j2)
                #pragma unroll
                for (int i2 = 0; i2 < 8; ++i2)
                    as_[tcl * 8 + j2][tr * 8 + i2] = acc[i2][j2];
        }
        #pragma unroll
        for (int it = 0; it < 4; ++it) {
            int id = tid + it * 256;
            int k = id >> 5;
            int c4 = id & 31;
            int s4 = ((c4 & 1) << 4) | (c4 >> 1);
            *reinterpret_cast<float4*>(&wsd[k][s4 * 4]) =
                *reinterpret_cast<const float4*>(&VT[(size_t)(kk + k) * 128 + c4 * 4]);
        }
        __syncthreads();
        #pragma unroll 4
        for (int k = 0; k < 32; ++k) {
            float4 a0 = *reinterpret_cast<const float4*>(&as_[k][tr * 8]);
            float4 a1 = *reinterpret_cast<const float4*>(&as_[k][tr * 8 + 4]);
            float4 b0 = *reinterpret_cast<const float4*>(&wsd[k][tc * 4]);
            float4 b1 = *reinterpret_cast<const float4*>(&wsd[k][64 + tc * 4]);
            float av[8] = {a0.x, a0.y, a0.z, a0.w, a1.x, a1.y, a1.z, a1.w};
            float bv[8] = {b0.x, b0.y, b0.z, b0.w, b1.x, b1.y, b1.z, b1.w};
            #pragma unroll
            for (int i2 = 0; i2 < 8; ++i2)
                #pragma unroll
                for (int j2 = 0; j2 < 8; ++j2)
                    acc2[i2][j2] += av[i2] * bv[j2];
        }
    }
    #pragma unroll
    for (int i2 = 0; i2 < 8; ++i2) {
        int grow = row0 + tr * 8 + i2;
        if (grow < n) {
            float4 o0 = {acc2[i2][0], acc2[i2][1], acc2[i2][2], acc2[i2][3]};
            float4 o1 = {acc2[i2][4], acc2[i2][5], acc2[i2][6], acc2[i2][7]};
            *reinterpret_cast<float4*>(&u[(size_t)grow * 128 + tc * 8])     = o0;
            *reinterpret_cast<float4*>(&u[(size_t)grow * 128 + tc * 8 + 4]) = o1;
        }
    }
}

// ---- kernel 3: per-node attention, 1 WAVE = 1 BLOCK = 1 node (R10, unchanged) ----
__global__ __launch_bounds__(64, 5) void node_attn(
    const int* __restrict__ nlist,
    const float* __restrict__ G,
    float* uy,                      // in: u = xQK@V^T ; out: y (aliased)
    float* __restrict__ c0a,
    int n)
{
    __shared__ __align__(16) float Bs[2048];   // 16 rows x 128 floats (line-permuted)
    __shared__ __align__(16) float Ts[16];

    const int l  = threadIdx.x;   // 0..63
    const int g  = l >> 2;        // row/group 0..15
    const int jj = l & 3;         // 32-float chunk
    const int i  = blockIdx.x;

    int nlv = 0;
    if (l < 16) nlv = nlist[(size_t)i * 16 + l];
    unsigned long long mb = __ballot(l < 16 ? (nlv != n - 1) : 0);

    // async gather x-half of G[nl] -> LDS (8 instrs, 2 rows each)
    {
        int sub   = l & 31;                          // LDS line within row
        int sigma = ((sub & 3) << 3) | (sub >> 2);   // global line it must hold
        int half  = l >> 5;
        #pragma unroll
        for (int p = 0; p < 8; ++p) {
            int nr = __shfl(nlv, 2 * p + half, 64);
            const float* src = &G[(size_t)nr * 256 + sigma * 4];
            __builtin_amdgcn_global_load_lds(
                (const __attribute__((address_space(1))) unsigned int*)src,
                (__attribute__((address_space(3))) unsigned int*)&Bs[p * 256],
                16, 0, 0);
        }
    }

    // s200 = xQK[i] . x[i] while the gather is in flight
    float2 qa = *reinterpret_cast<const float2*>(&G[(size_t)i * 256 + 128 + l * 2]);
    float2 xa = *reinterpret_cast<const float2*>(&G[(size_t)i * 256 + l * 2]);
    float s200 = qa.x * xa.x + qa.y * xa.y;
    s200 = dpp_add<DPP_XOR1>(s200);
    s200 = dpp_add<DPP_XOR2>(s200);
    s200 = dpp_add<DPP_XOR7>(s200);
    s200 = dpp_add<DPP_XOR15>(s200);
    s200 += __shfl_xor(s200, 16, 64);
    s200 += __shfl_xor(s200, 32, 64);

    // A = xQK[nl_g] chunk jj (k-ascending), overlaps the gather
    int nl_g = __shfl(nlv, g, 64);
    float4 A[8];
    {
        const float* ab = &G[(size_t)nl_g * 256 + 128 + jj * 32];
        #pragma unroll
        for (int k4 = 0; k4 < 8; ++k4)
            A[k4] = *reinterpret_cast<const float4*>(&ab[k4 * 4]);
    }

    wave_vm_fence();

    // stage-1: sc[c] = xQK[nl_g] . x[nl_c]; leaky -> mask -> *scare -> row softmax
    float a[16];
    {
        float sc[16];
        #pragma unroll
        for (int c = 0; c < 16; ++c) {
            const float* bb = &Bs[c * 128 + jj * 4];
            float acc = 0.f;
            #pragma unroll
            for (int k4 = 0; k4 < 8; ++k4) {
                float4 b = *reinterpret_cast<const float4*>(&bb[k4 * 16]);
                acc += A[k4].x * b.x + A[k4].y * b.y + A[k4].z * b.z + A[k4].w * b.w;
            }
            acc = dpp_add<DPP_XOR1>(acc);
            acc = dpp_add<DPP_XOR2>(acc);
            sc[c] = acc;
        }
        bool rlive = (mb >> g) & 1ULL;
        float m = -3.0e38f;
        #pragma unroll
        for (int c = 0; c < 16; ++c) {
            float s = sc[c];
            float slr = s > 0.f ? s : 0.01f * s;
            bool live = rlive && ((mb >> c) & 1ULL);
            float sm = (live ? slr : NEG_CONST) * SCARE;
            sc[c] = sm;
            m = fmaxf(m, sm);
        }
        float ssum = 0.f;
        #pragma unroll
        for (int c = 0; c < 16; ++c) { float p = __expf(sc[c] - m); a[c] = p; ssum += p; }
        float rs = 1.f / ssum;
        #pragma unroll
        for (int c = 0; c < 16; ++c) a[c] *= rs;
    }

    // t_g = u[i] . x[nl_g]  (k4 staggered by g; 8 lanes per 4-bank group = floor)
    {
        float acc = 0.f;
        #pragma unroll
        for (int k4 = 0; k4 < 8; ++k4) {
            int kx = (k4 + g) & 7;
            float4 b  = *reinterpret_cast<const float4*>(&Bs[g * 128 + kx * 16 + jj * 4]);
            float4 uu = *reinterpret_cast<const float4*>(&uy[(size_t)i * 128 + jj * 32 + kx * 4]);
            acc += uu.x * b.x + uu.y * b.y + uu.z * b.z + uu.w * b.w;
        }
        acc = dpp_add<DPP_XOR1>(acc);
        acc = dpp_add<DPP_XOR2>(acc);
        if (jj == 0) Ts[g] = acc;
    }
    wave_lds_fence();
    float tarr[16];
    {
        #pragma unroll
        for (int q4 = 0; q4 < 4; ++q4) {
            float4 t4 = *reinterpret_cast<const float4*>(&Ts[q4 * 4]);
            tarr[q4 * 4 + 0] = t4.x; tarr[q4 * 4 + 1] = t4.y;
            tarr[q4 * 4 + 2] = t4.z; tarr[q4 * 4 + 3] = t4.w;
        }
    }

    // stage-2 logit for this group (j = g+1): scare -> leaky -> mask
    float lg = 0.f;
    #pragma unroll
    for (int k = 0; k < 16; ++k) lg += a[k] * tarr[k];
    {
        float v = lg * SCARE;
        v = v > 0.f ? v : 0.01f * v;
        lg = ((mb >> g) & 1ULL) ? v : NEG_CONST;
    }
    float v0 = s200 * SCARE;
    v0 = v0 > 0.f ? v0 : 0.01f * v0;

    float m17 = lg;
    m17 = dpp_max<DPP_XOR7>(m17);
    m17 = dpp_max<DPP_XOR15>(m17);
    m17 = fmaxf(m17, __shfl_xor(m17, 16, 64));
    m17 = fmaxf(m17, __shfl_xor(m17, 32, 64));
    m17 = fmaxf(m17, v0);
    float pg = __expf(lg - m17);
    float sg = pg;
    sg = dpp_add<DPP_XOR7>(sg);
    sg = dpp_add<DPP_XOR15>(sg);
    sg += __shfl_xor(sg, 16, 64);
    sg += __shfl_xor(sg, 32, 64);
    float p0 = __expf(v0 - m17);
    float inv = 1.f / (sg + p0);
    float a2g = pg * inv;   // a2[g+1] (replicated within quad)
    float a20 = p0 * inv;

    // w[k] = sum_g a2[g+1] * a[g][k]
    float w[16];
    #pragma unroll
    for (int k = 0; k < 16; ++k) {
        float wv = a2g * a[k];
        wv = dpp_add<DPP_XOR7>(wv);
        wv = dpp_add<DPP_XOR15>(wv);
        wv += __shfl_xor(wv, 16, 64);
        wv += __shfl_xor(wv, 32, 64);
        w[k] = wv;
    }

    // y-loop, line-parallel (conflict-free)
    {
        int h   = l >> 5;
        int tau = l & 31;
        float y0 = 0.f, y1 = 0.f, y2 = 0.f, y3 = 0.f;
        #pragma unroll
        for (int k = 0; k < 8; ++k) {
            float wk = h ? w[k + 8] : w[k];
            const float* bp = &Bs[(h * 8 + k) * 128 + tau * 4];
            float4 b = *reinterpret_cast<const float4*>(bp);
            y0 += wk * b.x; y1 += wk * b.y; y2 += wk * b.z; y3 += wk * b.w;
        }
        y0 += __shfl_xor(y0, 32, 64);
        y1 += __shfl_xor(y1, 32, 64);
        y2 += __shfl_xor(y2, 32, 64);
        y3 += __shfl_xor(y3, 32, 64);
        if (h == 0) {
            int sigma = ((tau & 3) << 3) | (tau >> 2);   // global line held by tau
            float4 yw = {y0, y1, y2, y3};
            *reinterpret_cast<float4*>(&uy[(size_t)i * 128 + sigma * 4]) = yw;
        }
    }
    if (l == 0) c0a[i] = a20;
}

// ---- kernel 4: fused epilogue: out = normalize((c0*x + y@V) @ V) ----
__global__ __launch_bounds__(256) void ep_fused(
    const float* __restrict__ y, const float* __restrict__ G,
    const float* __restrict__ c0a, const float* __restrict__ Vw,
    float* __restrict__ outp, int n)
{
    __shared__ __align__(16) float as_[32][132];  // [k][row] (transposed)
    __shared__ __align__(16) float wsd[32][132];  // [k][slot] (de-interleaved)

    int row0 = blockIdx.x * 128;
    int tid = threadIdx.x;
    int tr = tid >> 4, tc = tid & 15;

    float acc[8][8] = {};
    for (int kk = 0; kk < 128; kk += 32) {
        #pragma unroll
        for (int it = 0; it < 4; ++it) {
            int id = tid + it * 256;
            int r = id >> 3;
            int f = id & 7;
            int grow = row0 + r;
            float4 v = (grow < n)
                ? *reinterpret_cast<const float4*>(&y[(size_t)grow * 128 + kk + f * 4])
                : make_float4(0.f, 0.f, 0.f, 0.f);
            as_[f * 4 + 0][r] = v.x; as_[f * 4 + 1][r] = v.y;
            as_[f * 4 + 2][r] = v.z; as_[f * 4 + 3][r] = v.w;
        }
        #pragma unroll
        for (int it = 0; it < 4; ++it) {
            int id = tid + it * 256;
            int k = id >> 5;
            int c4 = id & 31;
            int s4 = ((c4 & 1) << 4) | (c4 >> 1);
            *reinterpret_cast<float4*>(&wsd[k][s4 * 4]) =
                *reinterpret_cast<const float4*>(&Vw[(size_t)(kk + k) * 128 + c4 * 4]);
        }
        __syncthreads();
        #pragma unroll 4
        for (int k = 0; k < 32; ++k) {
            float4 a0 = *reinterpret_cast<const float4*>(&as_[k][tr * 8]);
            float4 a1 = *reinterpret_cast<const float4*>(&as_[k][tr * 8 + 4]);
            float4 b0 = *reinterpret_cast<const float4*>(&wsd[k][tc * 4]);
            float4 b1 = *reinterpret_cast<const float4*>(&wsd[k][64 + tc * 4]);
            float av[8] = {a0.x, a0.y, a0.z, a0.w, a1.x, a1.y, a1.z, a1.w};
            float bv[8] = {b0.x, b0.y, b0.z, b0.w, b1.x, b1.y, b1.z, b1.w};
            #pragma unroll
            for (int i2 = 0; i2 < 8; ++i2)
                #pragma unroll
                for (int j2 = 0; j2 < 8; ++j2)
                    acc[i2][j2] += av[i2] * bv[j2];
        }
        __syncthreads();
    }

    // t = acc + c0 * x   (x-half of G, stride 256)
    #pragma unroll
    for (int i2 = 0; i2 < 8; ++i2) {
        int grow = row0 + tr * 8 + i2;
        if (grow < n) {
            float c0v = c0a[grow];
            float4 g0 = *reinterpret_cast<const float4*>(&G[(size_t)grow * 256 + tc * 8]);
            float4 g1 = *reinterpret_cast<const float4*>(&G[(size_t)grow * 256 + tc * 8 + 4]);
            acc[i2][0] += c0v * g0.x; acc[i2][1] += c0v * g0.y;
            acc[i2][2] += c0v * g0.z; acc[i2][3] += c0v * g0.w;
            acc[i2][4] += c0v * g1.x; acc[i2][5] += c0v * g1.y;
            acc[i2][6] += c0v * g1.z; acc[i2][7] += c0v * g1.w;
        }
    }

    // phase 2: out = normalize(t @ V)
    float acc2[8][8] = {};
    for (int kk = 0; kk < 128; kk += 32) {
        __syncthreads();
        int tcl = tc - (kk >> 3);
        if (tcl >= 0 && tcl < 4) {
            #pragma unroll
            for (int j2 = 0; j2 < 8; ++j2)
                #pragma unroll
                for (int i2 = 0; i2 < 8; ++i2)
                    as_[tcl * 8 + j2][tr * 8 + i2] = acc[i2][j2];
        }
        #pragma unroll
        for (int it = 0; it < 4; ++it) {
            int id = tid + it * 256;
            int k = id >> 5;
            int c4 = id & 31;
            int s4 = ((c4 & 1) << 4) | (c4 >> 1);
            *reinterpret_cast<float4*>(&wsd[k][s4 * 4]) =
                *reinterpret_cast<const float4*>(&Vw[(size_t)(kk + k) * 128 + c4 * 4]);
        }
        __syncthreads();
        #pragma unroll 4
        for (int k = 0; k < 32; ++k) {
            float4 a0 = *reinterpret_cast<const float4*>(&as_[k][tr * 8]);
            float4 a1 = *reinterpret_cast<const float4*>(&as_[k][tr * 8 + 4]);
            float4 b0 = *reinterpret_cast<const float4*>(&wsd[k][tc * 4]);
            float4 b1 = *reinterpret_cast<const float4*>(&wsd[k][64 + tc * 4]);
            float av[8] = {a0.x, a0.y, a0.z, a0.w, a1.x, a1.y, a1.z, a1.w};
            float bv[8] = {b0.x, b0.y, b0.z, b0.w, b1.x, b1.y, b1.z, b1.w};
            #pragma unroll
            for (int i2 = 0; i2 < 8; ++i2)
                #pragma unroll
                for (int j2 = 0; j2 < 8; ++j2)
                    acc2[i2][j2] += av[i2] * bv[j2];
        }
    }

    #pragma unroll
    for (int i2 = 0; i2 < 8; ++i2) {
        int grow = row0 + tr * 8 + i2;
        float ss = 0.f;
        #pragma unroll
        for (int j2 = 0; j2 < 8; ++j2) ss += acc2[i2][j2] * acc2[i2][j2];
        ss = dpp_add<DPP_XOR1>(ss);
        ss = dpp_add<DPP_XOR2>(ss);
        ss = dpp_add<DPP_XOR7>(ss);
        ss = dpp_add<DPP_XOR15>(ss);
        float d = fmaxf(sqrtf(ss), 1e-12f);
        float rd = 1.f / d;
        if (grow < n) {
            float4 o0 = {acc2[i2][0] * rd, acc2[i2][1] * rd, acc2[i2][2] * rd, acc2[i2][3] * rd};
            float4 o1 = {acc2[i2][4] * rd, acc2[i2][5] * rd, acc2[i2][6] * rd, acc2[i2][7] * rd};
            *reinterpret_cast<float4*>(&outp[(size_t)grow * 128 + tc * 8])     = o0;
            *reinterpret_cast<float4*>(&outp[(size_t)grow * 128 + tc * 8 + 4]) = o1;
        }
    }
}

extern "C" void kernel_launch(void* const* d_in, const int* in_sizes, int n_in,
                              void* d_out, int out_size, void* d_ws, size_t ws_size,
                              hipStream_t stream) {
    const float* x     = (const float*)d_in[0];
    const int*   nlist = (const int*)d_in[1];
    const float* Q     = (const float*)d_in[2];
    const float* K     = (const float*)d_in[3];
    const float* V     = (const float*)d_in[4];
    float* out = (float*)d_out;
    int n = in_sizes[0] / 128;   // 50000

    float* ws   = (float*)d_ws;
    float* QKt  = ws;                    // 16384
    float* VT   = ws + 16384;            // 16384
    float* c0a  = ws + 32768;            // n
    float* G    = c0a + n;               // n*256
    float* uarr = G + (size_t)n * 256;   // n*128  (y aliases this after node_attn)

    small_qkt_vt<<<dim3(16, 2), 256, 0, stream>>>(Q, K, V, QKt, VT);
    proj_fused<<<(n + 127) / 128, 256, 0, stream>>>(x, QKt, VT, G, uarr, n);
    node_attn<<<n, 64, 0, stream>>>(nlist, G, uarr, c0a, n);
    ep_fused<<<(n + 127) / 128, 256, 0, stream>>>(uarr, G, c0a, V, out, n);
}